// Round 16
// baseline (1013.596 us; speedup 1.0000x reference)
//
#include <hip/hip_runtime.h>

#define NN 50000
#define NE 800000
#define NG 128
#define NL 3
#define NGRP (NE / 16)
#define SCANB ((NN + 1023) / 1024)

typedef __attribute__((ext_vector_type(8))) short short8;
typedef __attribute__((ext_vector_type(4))) float f32x4;
typedef __attribute__((ext_vector_type(4))) int i32x4;

union FragU { i32x4 i; short8 s; };

// silu via v_rcp_f32 (1-ulp): saves ~6 VALU vs full-precision divide; error
// ~1e-7 abs, 4 orders below the 0.0059 bf16-split floor (absmax must not move).
__device__ __forceinline__ float silu_f(float x) {
  return x * __builtin_amdgcn_rcpf(1.f + __expf(-x));
}
__device__ __forceinline__ float rdl(float v, int l) {
  return __int_as_float(__builtin_amdgcn_readlane(__float_as_int(v), l));
}
__device__ __forceinline__ float wave_sum(float v) {
#pragma unroll
  for (int m = 1; m < 64; m <<= 1) v += __shfl_xor(v, m, 64);
  return v;
}

__device__ __forceinline__ unsigned f2u(float x) { return __float_as_uint(x); }
__device__ __forceinline__ float hi_part(float x) {
  return __uint_as_float(f2u(x) & 0xffff0000u);
}
// pack two fp32 -> (bf16,bf16) dword via truncation; e0 in low half
__device__ __forceinline__ unsigned pk_hi(float e0, float e1) {
  return __builtin_amdgcn_perm(f2u(e1), f2u(e0), 0x07060302u);
}

__device__ __forceinline__ f32x4 mfma16(i32x4 a, i32x4 b, f32x4 c) {
  FragU ua, ub; ua.i = a; ub.i = b;
  return __builtin_amdgcn_mfma_f32_16x16x32_bf16(ua.s, ub.s, c, 0, 0, 0);
}

// split 8 fp32 into hi/lo bf16x8 fragments (element order: k ascending)
__device__ __forceinline__ void split8(const float* x, i32x4& fh, i32x4& fl) {
#pragma unroll
  for (int i = 0; i < 4; ++i) {
    const float a = x[2 * i], b = x[2 * i + 1];
    fh[i] = (int)pk_hi(a, b);
    fl[i] = (int)pk_hi(a - hi_part(a), b - hi_part(b));
  }
}

// bounded B-frag (hi/lo) for W[k][n]: rows k0..k0+31, col n (ld=64)
__device__ __forceinline__ void wfrag(const float* __restrict__ W, int nrows, int k0,
                                      int n, int lane, i32x4& fh, i32x4& fl) {
  const int kb = k0 + ((lane >> 4) << 3);
  float x[8];
#pragma unroll
  for (int j = 0; j < 8; ++j) {
    const int k = kb + j;
    x[j] = (k < nrows) ? W[k * 64 + n] : 0.f;
  }
  split8(x, fh, fl);
}

// ---------------- init / small kernels ----------------
// merged prep: h/hpk init + all zeroing in one pass
__global__ __launch_bounds__(256) void k_prep(const int* __restrict__ nt,
                                              const float* __restrict__ emb,
                                              const float* __restrict__ pos_in,
                                              float* __restrict__ pos,
                                              float* __restrict__ deg,
                                              float* __restrict__ g,
                                              float* __restrict__ gcnt,
                                              float* __restrict__ agg,
                                              float* __restrict__ posd,
                                              float* __restrict__ h,
                                              unsigned short* __restrict__ hpk) {
  int idx = blockIdx.x * 256 + threadIdx.x;
  if (idx < NN * 64) {
    agg[idx] = 0.f;
    const int node = idx >> 6, c = idx & 63;
    const float v = emb[nt[node] * 64 + c];
    h[idx] = v;
    const unsigned hb = f2u(v) & 0xffff0000u;
    const float lo = v - __uint_as_float(hb);
    hpk[node * 128 + c] = (unsigned short)(hb >> 16);
    hpk[node * 128 + 64 + c] = (unsigned short)(f2u(lo) >> 16);
  }
  if (idx < NN * 3) { pos[idx] = pos_in[idx]; posd[idx] = 0.f; }
  if (idx < NN) deg[idx] = 0.f;
  if (idx < NG * 64) g[idx] = 0.f;
  if (idx < NG) gcnt[idx] = 0.f;
}

__global__ __launch_bounds__(256) void k_hist(const int* __restrict__ ei,
                                              float* __restrict__ deg) {
  int e = blockIdx.x * 256 + threadIdx.x;
  if (e < NE) atomicAdd(&deg[ei[NE + e]], 1.f);
}

// hierarchical exclusive scan of deg -> cursor (counting-sort setup), part A
__global__ __launch_bounds__(1024) void k_scanA(const float* __restrict__ deg,
                                                int* __restrict__ cursor,
                                                int* __restrict__ bsum) {
  __shared__ int wsum[16];
  const int tid = threadIdx.x, lane = tid & 63, w = tid >> 6;
  const int i = blockIdx.x * 1024 + tid;
  const int v = (i < NN) ? (int)deg[i] : 0;
  int x = v;
#pragma unroll
  for (int o = 1; o < 64; o <<= 1) {
    const int y = __shfl_up(x, o, 64);
    if (lane >= o) x += y;
  }
  if (lane == 63) wsum[w] = x;
  __syncthreads();
  if (tid == 0) {
    int acc = 0;
#pragma unroll
    for (int k = 0; k < 16; ++k) { const int t = wsum[k]; wsum[k] = acc; acc += t; }
    bsum[blockIdx.x] = acc;
  }
  __syncthreads();
  if (i < NN) cursor[i] = wsum[w] + (x - v);
}

// part B: add prefix of block sums
__global__ __launch_bounds__(1024) void k_scanB(int* __restrict__ cursor,
                                                const int* __restrict__ bsum) {
  __shared__ int s_off;
  if (threadIdx.x == 0) {
    int a = 0;
    for (int k = 0; k < (int)blockIdx.x; ++k) a += bsum[k];
    s_off = a;
  }
  __syncthreads();
  const int i = blockIdx.x * 1024 + threadIdx.x;
  if (i < NN) cursor[i] += s_off;
}

// scatter edges into dst-sorted order (stable-enough counting sort)
__global__ __launch_bounds__(256) void k_scatter(const int* __restrict__ ei,
                                                 const float* __restrict__ eattr,
                                                 int* __restrict__ cursor,
                                                 int* __restrict__ ssrc,
                                                 int* __restrict__ sdst,
                                                 float4* __restrict__ seattr) {
  const int e = blockIdx.x * 256 + threadIdx.x;
  if (e < NE) {
    const int s = ei[e], d = ei[NE + e];
    const int p = atomicAdd(&cursor[d], 1);
    ssrc[p] = s;
    sdst[p] = d;
    seattr[p] = *(const float4*)(eattr + 4 * (size_t)e);
  }
}

__global__ __launch_bounds__(256) void k_cnt(const int* __restrict__ batch,
                                             float* __restrict__ deg,
                                             float* __restrict__ gcnt) {
  int i = blockIdx.x * 256 + threadIdx.x;
  if (i < NN) {
    deg[i] = fmaxf(deg[i], 1.f);
    atomicAdd(&gcnt[batch[i]], 1.f);
  }
}

// pos update; re-zeroes posd for the next layer
__global__ __launch_bounds__(256) void k_pos(float* __restrict__ pos,
                                             float* __restrict__ posd,
                                             const float* __restrict__ deg) {
  int idx = blockIdx.x * 256 + threadIdx.x;
  if (idx < NN * 3) {
    pos[idx] += posd[idx] / deg[idx / 3];
    posd[idx] = 0.f;
  }
}

#define STORE_PAIR(base, row, toff, v)                                          \
  {                                                                             \
    const float vp_ = __shfl_xor((v), 1, 64);                                   \
    if (!(m & 1)) {                                                             \
      const int off_ = (row) * 128 + ((((toff) + m * 2)) ^ (((row) & 7) << 4)); \
      *(unsigned*)((base) + off_) = pk_hi((v), vp_);                            \
      *(unsigned*)((base) + 2048 + off_) =                                      \
          pk_hi((v)-hi_part(v), vp_ - hi_part(vp_));                            \
    }                                                                           \
  }

// ---------------- edge message kernel (wave-solo, dst-sorted, 12 waves) -------
// R15 CONFIG, byte-identical (best measured: 178us, VGPR 84, FETCH 134MB,
// WRITE 62MB, VALUBusy 49%, MfmaUtil 21.5%): rcp-silu + balanced partition.
// LAW (R5/R9/R11/R13): backend fixes the VGPR budget by its waves/EU heuristic
// (84 @ 768thr, 64 @ 1024thr) and will NOT expand it for a larger live set --
// added live state becomes remat/spill traffic. Only changes that REDUCE live
// state or issued work are safe.
// NOTE (R8): bf16-split GEMV budgeted for EDGE path only; node MLP stays fp32.
__global__ __launch_bounds__(768, 3) void k_edge(
    const unsigned short* __restrict__ hpk, const float* __restrict__ pos,
    const int* __restrict__ ssrc, const int* __restrict__ sdst,
    const float4* __restrict__ seattr,
    const float* __restrict__ W1, const float* __restrict__ B1,
    const float* __restrict__ W2, const float* __restrict__ B2,
    const float* __restrict__ C1, const float* __restrict__ CB1,
    const float* __restrict__ C2, const float* __restrict__ CB2,
    float* __restrict__ agg, float* __restrict__ posd) {
  __shared__ i32x4 smem[7680];  // 72KB table + 12 waves * 4KB planes = 120KB

  const int tid = threadIdx.x;
  const int lane = tid & 63;
  const int w = tid >> 6;  // 0..11
  const int m = lane & 15;
  const int quad = lane >> 4;

  // ---- one-time: stage weight fragment tables (36 jobs over 12 waves) ----
  for (int j = w; j < 36; j += 12) {
    int s, t, nrows, hb, lb;
    const float* W;
    if (j < 20)      { s = j >> 2; t = j & 3; W = W1; nrows = 133; hb = 0; lb = 1280; }
    else if (j < 28) { const int q = j - 20; s = q >> 2; t = q & 3; W = W2; nrows = 64; hb = 2560; lb = 3072; }
    else             { const int q = j - 28; s = q >> 2; t = q & 3; W = C1; nrows = 64; hb = 3584; lb = 4096; }
    i32x4 fh, fl;
    wfrag(W, nrows, 32 * s, t * 16 + m, lane, fh, fl);
    smem[hb + (s * 4 + t) * 64 + lane] = fh;
    smem[lb + (s * 4 + t) * 64 + lane] = fl;
  }
  __syncthreads();

  // per-lane scalars
  float eb1t[4], eb2t[4], cb1t[4], cw2t[4];
#pragma unroll
  for (int t = 0; t < 4; ++t) {
    eb1t[t] = B1[t * 16 + m];
    eb2t[t] = B2[t * 16 + m];
    cb1t[t] = CB1[t * 16 + m];
    cw2t[t] = C2[t * 16 + m];
  }
  const float cb2v = CB2[0];

  char* pl = (char*)(smem + 4608) + w * 4096;  // wave plane: hi@0, lo@+2048
  const char* hB = (const char*)hpk;

  // balanced contiguous tile range: first r waves take q+1 tiles, rest q
  const int gw = blockIdx.x * 12 + w;
  const int nwv = gridDim.x * 12;
  const int q_ = NGRP / nwv;
  const int r_ = NGRP % nwv;
  const int gbeg = gw * q_ + min(gw, r_);
  const int gend = gbeg + q_ + (gw < r_ ? 1 : 0);

  int es = 0, ed = 0;
  if (gbeg < gend) {
    es = ssrc[gbeg * 16 + m];
    ed = sdst[gbeg * 16 + m];
  }

  for (int g = gbeg; g < gend; ++g) {
    const int e0 = g * 16;
    const int ces = es, ced = ed;
    if (g + 1 < gend) {
      es = ssrc[(g + 1) * 16 + m];
      ed = sdst[(g + 1) * 16 + m];
    }

    // ---- gathers: lane's edge-m node rows, frag-ready ----
    i32x4 fh[4], fl[4];
#pragma unroll
    for (int s = 0; s < 4; ++s) {
      const unsigned node = (unsigned)(s < 2 ? ced : ces);
      const unsigned off = node * 256u + (unsigned)((s & 1) * 64 + quad * 16);
      fh[s] = *(const i32x4*)(hB + off);
      fl[s] = *(const i32x4*)(hB + off + 128);
    }

    // ---- per-edge tail data (lanes 0..15) ----
    float rx = 0.f, ry = 0.f, rz = 0.f, d2v = 0.f;
    float ea0 = 0.f, ea1 = 0.f, ea2 = 0.f, ea3 = 0.f;
    if (lane < 16) {
      rx = pos[ced * 3 + 0] - pos[ces * 3 + 0];
      ry = pos[ced * 3 + 1] - pos[ces * 3 + 1];
      rz = pos[ced * 3 + 2] - pos[ces * 3 + 2];
      d2v = rx * rx + ry * ry + rz * rz;
      const float4 ea = seattr[e0 + lane];
      ea0 = ea.x; ea1 = ea.y; ea2 = ea.z; ea3 = ea.w;
    }

    // tail A-frag (k=128..159): quad0 = [d2, ea0..3, 0...], quads 1-3 zero
    i32x4 th, tl;
    {
      float x0 = __shfl(d2v, m), x1 = __shfl(ea0, m), x2 = __shfl(ea1, m),
            x3 = __shfl(ea2, m), x4 = __shfl(ea3, m);
      if (quad) { x0 = x1 = x2 = x3 = x4 = 0.f; }
      float xt[8] = {x0, x1, x2, x3, x4, 0.f, 0.f, 0.f};
      split8(xt, th, tl);
    }

    // ---- GEMV1: m_in[16x160] @ W1[160x64] ----
#pragma unroll
    for (int t = 0; t < 4; ++t) {
      f32x4 P = {eb1t[t], eb1t[t], eb1t[t], eb1t[t]}, Q = {0.f, 0.f, 0.f, 0.f};
#pragma unroll
      for (int s = 0; s < 4; ++s) {
        const i32x4 wh = smem[(s * 4 + t) * 64 + lane];
        const i32x4 wl = smem[1280 + (s * 4 + t) * 64 + lane];
        P = mfma16(fh[s], wh, P);
        Q = mfma16(fh[s], wl, Q);
        Q = mfma16(fl[s], wh, Q);
      }
      {  // tail k-step (s=4)
        const i32x4 wh = smem[(16 + t) * 64 + lane];
        const i32x4 wl = smem[1280 + (16 + t) * 64 + lane];
        P = mfma16(th, wh, P);
        Q = mfma16(th, wl, Q);
        Q = mfma16(tl, wh, Q);
      }
#pragma unroll
      for (int r = 0; r < 4; ++r) {
        const int row = quad * 4 + r;
        const float v = silu_f(P[r] + Q[r]);
        STORE_PAIR(pl, row, t * 32, v);
      }
    }

    // ---- GEMV2: m1[16x64] @ W2[64x64] ----
    i32x4 ah[2], al[2];
#pragma unroll
    for (int s = 0; s < 2; ++s) {
      const int off = m * 128 + ((s * 64 + quad * 16) ^ ((m & 7) << 4));
      ah[s] = *(const i32x4*)(pl + off);
      al[s] = *(const i32x4*)(pl + 2048 + off);
    }
    float mv[4][4];
#pragma unroll
    for (int t = 0; t < 4; ++t) {
      f32x4 P = {eb2t[t], eb2t[t], eb2t[t], eb2t[t]}, Q = {0.f, 0.f, 0.f, 0.f};
#pragma unroll
      for (int s = 0; s < 2; ++s) {
        const i32x4 wh = smem[2560 + (s * 4 + t) * 64 + lane];
        const i32x4 wl = smem[3072 + (s * 4 + t) * 64 + lane];
        P = mfma16(ah[s], wh, P);
        Q = mfma16(ah[s], wl, Q);
        Q = mfma16(al[s], wh, Q);
      }
#pragma unroll
      for (int r = 0; r < 4; ++r) {
        const int row = quad * 4 + r;
        mv[t][r] = silu_f(P[r] + Q[r]);
        STORE_PAIR(pl, row, t * 32, mv[t][r]);  // mm overwrites m1 (in-order DS)
      }
    }

    // ---- segmented agg scatter: runs of equal dst (sorted) reduce in-wave ----
    {
      const bool headp = (m == 0) || (ced != __shfl(ced, lane - 1, 64));
      unsigned rem = (unsigned)(__ballot(headp) & 0xFFFFull);
      while (rem) {
        const int hrow = __ffs((int)rem) - 1;
        rem &= rem - 1;
        const int nrow = rem ? (__ffs((int)rem) - 1) : 16;
        const int dstn = __shfl(ced, hrow, 64);
#pragma unroll
        for (int t = 0; t < 4; ++t) {
          float s = 0.f;
#pragma unroll
          for (int r = 0; r < 4; ++r) {
            const int row = quad * 4 + r;
            s += (row >= hrow && row < nrow) ? mv[t][r] : 0.f;
          }
          s += __shfl_xor(s, 16, 64);
          s += __shfl_xor(s, 32, 64);
          if (quad == 0) atomicAdd(&agg[(size_t)dstn * 64 + t * 16 + m], s);
        }
      }
    }

    // ---- coord MLP: silu(mm @ C1 + cb1) . cw2 summed over 64 cols ----
    i32x4 mh[2], ml[2];
#pragma unroll
    for (int s = 0; s < 2; ++s) {
      const int off = m * 128 + ((s * 64 + quad * 16) ^ ((m & 7) << 4));
      mh[s] = *(const i32x4*)(pl + off);
      ml[s] = *(const i32x4*)(pl + 2048 + off);
    }
    float tr[4] = {0.f, 0.f, 0.f, 0.f};
#pragma unroll
    for (int t = 0; t < 4; ++t) {
      f32x4 P = {cb1t[t], cb1t[t], cb1t[t], cb1t[t]}, Q = {0.f, 0.f, 0.f, 0.f};
#pragma unroll
      for (int s = 0; s < 2; ++s) {
        const i32x4 wh = smem[3584 + (s * 4 + t) * 64 + lane];
        const i32x4 wl = smem[4096 + (s * 4 + t) * 64 + lane];
        P = mfma16(mh[s], wh, P);
        Q = mfma16(mh[s], wl, Q);
        Q = mfma16(ml[s], wh, Q);
      }
#pragma unroll
      for (int r = 0; r < 4; ++r) tr[r] += silu_f(P[r] + Q[r]) * cw2t[t];
    }
#pragma unroll
    for (int mask = 1; mask < 16; mask <<= 1)
#pragma unroll
      for (int r = 0; r < 4; ++r) tr[r] += __shfl_xor(tr[r], mask, 64);

    // posd atomics: lane (rr = m>>2 -> row, cc = m&3 -> coord), per quad
    {
      const int rr = m >> 2, cc = m & 3;
      const int e = quad * 4 + rr;
      const float tv = ((rr & 2) ? ((rr & 1) ? tr[3] : tr[2])
                                 : ((rr & 1) ? tr[1] : tr[0])) + cb2v;
      const int d_ = __shfl(ced, e, 64);
      const float ax = __shfl(rx, e, 64), ay = __shfl(ry, e, 64),
                  az = __shfl(rz, e, 64);
      if (cc < 3) {
        const float rel = cc == 0 ? ax : (cc == 1 ? ay : az);
        atomicAdd(&posd[d_ * 3 + cc], rel * tv);
      }
    }
  }
}

// ---------------- node update kernel (fp32 readlane, 8-node batch) ----------
// MUST stay fp32 (R8: bf16-split here doubled absmax, failed threshold).
// Re-zeroes agg; on the last layer also fuses the batch-pool.
// Grid 768 blocks -> 3 blocks/CU (LDS 3x48KB=144 <= 160KB; ~70 VGPR fits the
// 170 cap at 12 waves/CU): 3 waves/SIMD latency hiding, up from 2 (R15: k_node
// was the largest non-edge cost, same starved regime k_edge escaped).
__global__ __launch_bounds__(256) void k_node(
    float* __restrict__ h, unsigned short* __restrict__ hpk,
    float* __restrict__ agg,
    const float* __restrict__ W1, const float* __restrict__ B1,
    const float* __restrict__ W2, const float* __restrict__ B2,
    const int* __restrict__ batch, float* __restrict__ gpool) {
  __shared__ float sW1[128 * 64];
  __shared__ float sW2[64 * 64];
  for (int i = threadIdx.x; i < 128 * 64; i += 256) sW1[i] = W1[i];
  for (int i = threadIdx.x; i < 64 * 64; i += 256) sW2[i] = W2[i];
  __syncthreads();
  const int lane = threadIdx.x & 63;
  const float nb1 = B1[lane], nb2 = B2[lane];
  const int wid = (blockIdx.x * 256 + threadIdx.x) >> 6;
  const int nw = (gridDim.x * 256) >> 6;
  for (int n0 = wid * 8; n0 < NN; n0 += nw * 8) {
    float hj[8], aj[8], a1[8];
#pragma unroll
    for (int i = 0; i < 8; ++i) {
      hj[i] = h[(size_t)(n0 + i) * 64 + lane];
      aj[i] = agg[(size_t)(n0 + i) * 64 + lane];
      a1[i] = nb1;
    }
#pragma unroll
    for (int i = 0; i < 8; ++i) agg[(size_t)(n0 + i) * 64 + lane] = 0.f;
#pragma unroll
    for (int k = 0; k < 64; ++k) {
      const float wv = sW1[k * 64 + lane];
#pragma unroll
      for (int i = 0; i < 8; ++i) a1[i] += rdl(hj[i], k) * wv;
    }
#pragma unroll
    for (int k = 0; k < 64; ++k) {
      const float wv = sW1[(64 + k) * 64 + lane];
#pragma unroll
      for (int i = 0; i < 8; ++i) a1[i] += rdl(aj[i], k) * wv;
    }
    float u[8], a2[8];
#pragma unroll
    for (int i = 0; i < 8; ++i) { u[i] = silu_f(a1[i]); a2[i] = nb2; }
#pragma unroll
    for (int k = 0; k < 64; ++k) {
      const float wv = sW2[k * 64 + lane];
#pragma unroll
      for (int i = 0; i < 8; ++i) a2[i] += rdl(u[i], k) * wv;
    }
    float hn[8];
#pragma unroll
    for (int i = 0; i < 8; ++i) {
      hn[i] = hj[i] + a2[i];
      h[(size_t)(n0 + i) * 64 + lane] = hn[i];
      const unsigned hb = f2u(hn[i]) & 0xffff0000u;
      const float lo = hn[i] - __uint_as_float(hb);
      hpk[(size_t)(n0 + i) * 128 + lane] = (unsigned short)(hb >> 16);
      hpk[(size_t)(n0 + i) * 128 + 64 + lane] = (unsigned short)(f2u(lo) >> 16);
    }
    if (gpool) {  // last layer: fused global-mean-pool accumulation
      float acc = 0.f;
      int curb = batch[n0];
#pragma unroll
      for (int i = 0; i < 8; ++i) {
        const int b = batch[n0 + i];
        if (b != curb) {
          atomicAdd(&gpool[curb * 64 + lane], acc);
          acc = 0.f;
          curb = b;
        }
        acc += hn[i];
      }
      atomicAdd(&gpool[curb * 64 + lane], acc);
    }
  }
}

// ---------------- pooled head: q-circuit + MLP ----------------
__global__ __launch_bounds__(256) void k_final(
    const float* __restrict__ g, const float* __restrict__ gcnt,
    const float* __restrict__ prew, const float* __restrict__ preb,
    const float* __restrict__ qw, const float* __restrict__ pw1,
    const float* __restrict__ pb1, const float* __restrict__ pw2,
    const float* __restrict__ pb2, float* __restrict__ out) {
  const int lane = threadIdx.x & 63;
  const int gid = (blockIdx.x * 256 + threadIdx.x) >> 6;
  if (gid >= NG) return;
  const float cnt = fmaxf(gcnt[gid], 1.f);
  const float gv = g[gid * 64 + lane] / cnt;
  float qin[4];
#pragma unroll
  for (int q = 0; q < 4; ++q)
    qin[q] = wave_sum(gv * prew[lane * 4 + q]) + preb[q];
  float sr[16], si[16];
#pragma unroll
  for (int i = 0; i < 16; ++i) { sr[i] = 0.f; si[i] = 0.f; }
  sr[0] = 1.f;
#pragma unroll
  for (int q = 0; q < 4; ++q) {  // RX(qin[q])
    const int mask = 8 >> q;
    float s, c;
    __sincosf(qin[q] * 0.5f, &s, &c);
#pragma unroll
    for (int i = 0; i < 16; ++i)
      if (!(i & mask)) {
        const int j = i | mask;
        const float ar = sr[i], ai = si[i], br = sr[j], bi = si[j];
        sr[i] = c * ar + s * bi; si[i] = c * ai - s * br;
        sr[j] = c * br + s * ai; si[j] = c * bi - s * ar;
      }
  }
#pragma unroll
  for (int l = 0; l < 2; ++l) {
#pragma unroll
    for (int q = 0; q < 4; ++q) {  // RY(qw[l][q])
      const int mask = 8 >> q;
      float s, c;
      __sincosf(qw[l * 4 + q] * 0.5f, &s, &c);
#pragma unroll
      for (int i = 0; i < 16; ++i)
        if (!(i & mask)) {
          const int j = i | mask;
          const float ar = sr[i], ai = si[i], br = sr[j], bi = si[j];
          sr[i] = c * ar - s * br; si[i] = c * ai - s * bi;
          sr[j] = s * ar + c * br; si[j] = s * ai + c * bi;
        }
    }
#pragma unroll
    for (int q = 0; q < 4; ++q) {  // CNOT q -> (q+1)%4
      const int mc = 8 >> q;
      const int mt = 8 >> ((q + 1) & 3);
#pragma unroll
      for (int i = 0; i < 16; ++i)
        if ((i & mc) && !(i & mt)) {
          const int j = i | mt;
          float t = sr[i]; sr[i] = sr[j]; sr[j] = t;
          t = si[i]; si[i] = si[j]; si[j] = t;
        }
    }
  }
  float qo[4] = {0.f, 0.f, 0.f, 0.f};
#pragma unroll
  for (int i = 0; i < 16; ++i) {
    const float p = sr[i] * sr[i] + si[i] * si[i];
#pragma unroll
    for (int q = 0; q < 4; ++q) qo[q] += ((i >> (3 - q)) & 1) ? -p : p;
  }
  float t = pb1[lane];
#pragma unroll
  for (int q = 0; q < 4; ++q) t += qo[q] * pw1[q * 64 + lane];
  const float r = wave_sum(silu_f(t) * pw2[lane]);
  if (lane == 0) out[gid] = r + pb2[0];
}

extern "C" void kernel_launch(void* const* d_in, const int* in_sizes, int n_in,
                              void* d_out, int out_size, void* d_ws, size_t ws_size,
                              hipStream_t stream) {
  (void)in_sizes; (void)n_in; (void)out_size; (void)ws_size;
  const int*   nt    = (const int*)d_in[0];
  const float* pos0  = (const float*)d_in[1];
  const int*   ei    = (const int*)d_in[2];
  const float* eattr = (const float*)d_in[3];
  const int*   batch = (const int*)d_in[4];
  const float* emb   = (const float*)d_in[5];
  const float* ew1   = (const float*)d_in[6];
  const float* eb1   = (const float*)d_in[7];
  const float* ew2   = (const float*)d_in[8];
  const float* eb2   = (const float*)d_in[9];
  const float* cw1   = (const float*)d_in[10];
  const float* cb1   = (const float*)d_in[11];
  const float* cw2   = (const float*)d_in[12];
  const float* cb2   = (const float*)d_in[13];
  const float* nw1   = (const float*)d_in[14];
  const float* nb1   = (const float*)d_in[15];
  const float* nw2   = (const float*)d_in[16];
  const float* nb2   = (const float*)d_in[17];
  const float* prew  = (const float*)d_in[18];
  const float* preb  = (const float*)d_in[19];
  const float* qw    = (const float*)d_in[20];
  const float* pw1   = (const float*)d_in[21];
  const float* pb1   = (const float*)d_in[22];
  const float* pw2   = (const float*)d_in[23];
  const float* pb2   = (const float*)d_in[24];
  float* out = (float*)d_out;

  float* ws   = (float*)d_ws;
  float* h    = ws;               // NN*64
  float* pos  = h + NN * 64;      // NN*3
  float* posd = pos + NN * 3;     // NN*3
  float* agg  = posd + NN * 3;    // NN*64
  float* deg  = agg + NN * 64;    // NN
  float* g    = deg + NN;         // NG*64
  float* gcnt = g + NG * 64;      // NG
  unsigned short* hpk = (unsigned short*)(gcnt + NG);  // NN*128 bf16 (hi|lo)
  float4* seattr = (float4*)(hpk + NN * 128);          // NE float4 (16B-aligned)
  int* ssrc   = (int*)(seattr + NE);                   // NE
  int* sdst   = ssrc + NE;                             // NE
  int* cursor = sdst + NE;                             // NN
  int* bsum   = cursor + NN;                           // SCANB

  k_prep<<<(NN * 64 + 255) / 256, 256, 0, stream>>>(nt, emb, pos0, pos, deg, g,
                                                    gcnt, agg, posd, h, hpk);
  k_hist<<<(NE + 255) / 256, 256, 0, stream>>>(ei, deg);
  k_scanA<<<SCANB, 1024, 0, stream>>>(deg, cursor, bsum);
  k_scanB<<<SCANB, 1024, 0, stream>>>(cursor, bsum);
  k_scatter<<<(NE + 255) / 256, 256, 0, stream>>>(ei, eattr, cursor, ssrc, sdst,
                                                  seattr);
  k_cnt<<<(NN + 255) / 256, 256, 0, stream>>>(batch, deg, gcnt);
  for (int l = 0; l < NL; ++l) {
    k_edge<<<256, 768, 0, stream>>>(hpk, pos, ssrc, sdst, seattr,
        ew1 + l * 133 * 64, eb1 + l * 64, ew2 + l * 64 * 64, eb2 + l * 64,
        cw1 + l * 64 * 64, cb1 + l * 64, cw2 + l * 64, cb2 + l, agg, posd);
    k_pos<<<(NN * 3 + 255) / 256, 256, 0, stream>>>(pos, posd, deg);
    k_node<<<768, 256, 0, stream>>>(h, hpk, agg, nw1 + l * 128 * 64, nb1 + l * 64,
                                    nw2 + l * 64 * 64, nb2 + l * 64, batch,
                                    (l == NL - 1) ? g : nullptr);
  }
  k_final<<<(NG * 64 + 255) / 256, 256, 0, stream>>>(g, gcnt, prew, preb, qw,
                                                     pw1, pb1, pw2, pb2, out);
}

// Round 17
// 997.170 us; speedup vs baseline: 1.0165x; 1.0165x over previous
//
#include <hip/hip_runtime.h>

#define NN 50000
#define NE 800000
#define NG 128
#define NL 3
#define NGRP (NE / 16)
#define SCANB ((NN + 1023) / 1024)

typedef __attribute__((ext_vector_type(8))) short short8;
typedef __attribute__((ext_vector_type(4))) float f32x4;
typedef __attribute__((ext_vector_type(4))) int i32x4;

union FragU { i32x4 i; short8 s; };

// silu via v_rcp_f32 (1-ulp): saves ~6 VALU vs full-precision divide; error
// ~1e-7 abs, 4 orders below the 0.0059 bf16-split floor (absmax must not move).
__device__ __forceinline__ float silu_f(float x) {
  return x * __builtin_amdgcn_rcpf(1.f + __expf(-x));
}
__device__ __forceinline__ float rdl(float v, int l) {
  return __int_as_float(__builtin_amdgcn_readlane(__float_as_int(v), l));
}
__device__ __forceinline__ float wave_sum(float v) {
#pragma unroll
  for (int m = 1; m < 64; m <<= 1) v += __shfl_xor(v, m, 64);
  return v;
}

__device__ __forceinline__ unsigned f2u(float x) { return __float_as_uint(x); }
__device__ __forceinline__ float hi_part(float x) {
  return __uint_as_float(f2u(x) & 0xffff0000u);
}
// pack two fp32 -> (bf16,bf16) dword via truncation; e0 in low half
__device__ __forceinline__ unsigned pk_hi(float e0, float e1) {
  return __builtin_amdgcn_perm(f2u(e1), f2u(e0), 0x07060302u);
}

__device__ __forceinline__ f32x4 mfma16(i32x4 a, i32x4 b, f32x4 c) {
  FragU ua, ub; ua.i = a; ub.i = b;
  return __builtin_amdgcn_mfma_f32_16x16x32_bf16(ua.s, ub.s, c, 0, 0, 0);
}

// split 8 fp32 into hi/lo bf16x8 fragments (element order: k ascending)
__device__ __forceinline__ void split8(const float* x, i32x4& fh, i32x4& fl) {
#pragma unroll
  for (int i = 0; i < 4; ++i) {
    const float a = x[2 * i], b = x[2 * i + 1];
    fh[i] = (int)pk_hi(a, b);
    fl[i] = (int)pk_hi(a - hi_part(a), b - hi_part(b));
  }
}

// bounded B-frag (hi/lo) for W[k][n]: rows k0..k0+31, col n (ld=64)
__device__ __forceinline__ void wfrag(const float* __restrict__ W, int nrows, int k0,
                                      int n, int lane, i32x4& fh, i32x4& fl) {
  const int kb = k0 + ((lane >> 4) << 3);
  float x[8];
#pragma unroll
  for (int j = 0; j < 8; ++j) {
    const int k = kb + j;
    x[j] = (k < nrows) ? W[k * 64 + n] : 0.f;
  }
  split8(x, fh, fl);
}

// ---------------- init / small kernels ----------------
// merged prep: h/hpk init + all zeroing in one pass
__global__ __launch_bounds__(256) void k_prep(const int* __restrict__ nt,
                                              const float* __restrict__ emb,
                                              const float* __restrict__ pos_in,
                                              float* __restrict__ pos,
                                              float* __restrict__ deg,
                                              float* __restrict__ g,
                                              float* __restrict__ gcnt,
                                              float* __restrict__ agg,
                                              float* __restrict__ posd,
                                              float* __restrict__ h,
                                              unsigned short* __restrict__ hpk) {
  int idx = blockIdx.x * 256 + threadIdx.x;
  if (idx < NN * 64) {
    agg[idx] = 0.f;
    const int node = idx >> 6, c = idx & 63;
    const float v = emb[nt[node] * 64 + c];
    h[idx] = v;
    const unsigned hb = f2u(v) & 0xffff0000u;
    const float lo = v - __uint_as_float(hb);
    hpk[node * 128 + c] = (unsigned short)(hb >> 16);
    hpk[node * 128 + 64 + c] = (unsigned short)(f2u(lo) >> 16);
  }
  if (idx < NN * 3) { pos[idx] = pos_in[idx]; posd[idx] = 0.f; }
  if (idx < NN) deg[idx] = 0.f;
  if (idx < NG * 64) g[idx] = 0.f;
  if (idx < NG) gcnt[idx] = 0.f;
}

__global__ __launch_bounds__(256) void k_hist(const int* __restrict__ ei,
                                              float* __restrict__ deg) {
  int e = blockIdx.x * 256 + threadIdx.x;
  if (e < NE) atomicAdd(&deg[ei[NE + e]], 1.f);
}

// hierarchical exclusive scan of deg -> cursor (counting-sort setup), part A
__global__ __launch_bounds__(1024) void k_scanA(const float* __restrict__ deg,
                                                int* __restrict__ cursor,
                                                int* __restrict__ bsum) {
  __shared__ int wsum[16];
  const int tid = threadIdx.x, lane = tid & 63, w = tid >> 6;
  const int i = blockIdx.x * 1024 + tid;
  const int v = (i < NN) ? (int)deg[i] : 0;
  int x = v;
#pragma unroll
  for (int o = 1; o < 64; o <<= 1) {
    const int y = __shfl_up(x, o, 64);
    if (lane >= o) x += y;
  }
  if (lane == 63) wsum[w] = x;
  __syncthreads();
  if (tid == 0) {
    int acc = 0;
#pragma unroll
    for (int k = 0; k < 16; ++k) { const int t = wsum[k]; wsum[k] = acc; acc += t; }
    bsum[blockIdx.x] = acc;
  }
  __syncthreads();
  if (i < NN) cursor[i] = wsum[w] + (x - v);
}

// part B: add prefix of block sums
__global__ __launch_bounds__(1024) void k_scanB(int* __restrict__ cursor,
                                                const int* __restrict__ bsum) {
  __shared__ int s_off;
  if (threadIdx.x == 0) {
    int a = 0;
    for (int k = 0; k < (int)blockIdx.x; ++k) a += bsum[k];
    s_off = a;
  }
  __syncthreads();
  const int i = blockIdx.x * 1024 + threadIdx.x;
  if (i < NN) cursor[i] += s_off;
}

// scatter edges into dst-sorted order (stable-enough counting sort)
__global__ __launch_bounds__(256) void k_scatter(const int* __restrict__ ei,
                                                 const float* __restrict__ eattr,
                                                 int* __restrict__ cursor,
                                                 int* __restrict__ ssrc,
                                                 int* __restrict__ sdst,
                                                 float4* __restrict__ seattr) {
  const int e = blockIdx.x * 256 + threadIdx.x;
  if (e < NE) {
    const int s = ei[e], d = ei[NE + e];
    const int p = atomicAdd(&cursor[d], 1);
    ssrc[p] = s;
    sdst[p] = d;
    seattr[p] = *(const float4*)(eattr + 4 * (size_t)e);
  }
}

__global__ __launch_bounds__(256) void k_cnt(const int* __restrict__ batch,
                                             float* __restrict__ deg,
                                             float* __restrict__ gcnt) {
  int i = blockIdx.x * 256 + threadIdx.x;
  if (i < NN) {
    deg[i] = fmaxf(deg[i], 1.f);
    atomicAdd(&gcnt[batch[i]], 1.f);
  }
}

// pos update; re-zeroes posd for the next layer
__global__ __launch_bounds__(256) void k_pos(float* __restrict__ pos,
                                             float* __restrict__ posd,
                                             const float* __restrict__ deg) {
  int idx = blockIdx.x * 256 + threadIdx.x;
  if (idx < NN * 3) {
    pos[idx] += posd[idx] / deg[idx / 3];
    posd[idx] = 0.f;
  }
}

#define STORE_PAIR(base, row, toff, v)                                          \
  {                                                                             \
    const float vp_ = __shfl_xor((v), 1, 64);                                   \
    if (!(m & 1)) {                                                             \
      const int off_ = (row) * 128 + ((((toff) + m * 2)) ^ (((row) & 7) << 4)); \
      *(unsigned*)((base) + off_) = pk_hi((v), vp_);                            \
      *(unsigned*)((base) + 2048 + off_) =                                      \
          pk_hi((v)-hi_part(v), vp_ - hi_part(vp_));                            \
    }                                                                           \
  }

// ---------------- edge message kernel (wave-solo, dst-sorted, 12 waves) -------
// R15 CONFIG, byte-identical (best measured: 176-178us, VGPR 84, FETCH 134MB,
// WRITE 62MB, VALUBusy 49%, MfmaUtil 21.5%): rcp-silu + balanced partition.
// LAW (R5/R9/R11/R13): backend fixes the VGPR budget by its waves/EU heuristic
// (84 @ 768thr, 64 @ 1024thr) and will NOT expand it for a larger live set --
// added live state becomes remat/spill traffic. Only changes that REDUCE live
// state or issued work are safe.
// NOTE (R8): bf16-split GEMV budgeted for EDGE path only; node MLP stays fp32.
__global__ __launch_bounds__(768, 3) void k_edge(
    const unsigned short* __restrict__ hpk, const float* __restrict__ pos,
    const int* __restrict__ ssrc, const int* __restrict__ sdst,
    const float4* __restrict__ seattr,
    const float* __restrict__ W1, const float* __restrict__ B1,
    const float* __restrict__ W2, const float* __restrict__ B2,
    const float* __restrict__ C1, const float* __restrict__ CB1,
    const float* __restrict__ C2, const float* __restrict__ CB2,
    float* __restrict__ agg, float* __restrict__ posd) {
  __shared__ i32x4 smem[7680];  // 72KB table + 12 waves * 4KB planes = 120KB

  const int tid = threadIdx.x;
  const int lane = tid & 63;
  const int w = tid >> 6;  // 0..11
  const int m = lane & 15;
  const int quad = lane >> 4;

  // ---- one-time: stage weight fragment tables (36 jobs over 12 waves) ----
  for (int j = w; j < 36; j += 12) {
    int s, t, nrows, hb, lb;
    const float* W;
    if (j < 20)      { s = j >> 2; t = j & 3; W = W1; nrows = 133; hb = 0; lb = 1280; }
    else if (j < 28) { const int q = j - 20; s = q >> 2; t = q & 3; W = W2; nrows = 64; hb = 2560; lb = 3072; }
    else             { const int q = j - 28; s = q >> 2; t = q & 3; W = C1; nrows = 64; hb = 3584; lb = 4096; }
    i32x4 fh, fl;
    wfrag(W, nrows, 32 * s, t * 16 + m, lane, fh, fl);
    smem[hb + (s * 4 + t) * 64 + lane] = fh;
    smem[lb + (s * 4 + t) * 64 + lane] = fl;
  }
  __syncthreads();

  // per-lane scalars
  float eb1t[4], eb2t[4], cb1t[4], cw2t[4];
#pragma unroll
  for (int t = 0; t < 4; ++t) {
    eb1t[t] = B1[t * 16 + m];
    eb2t[t] = B2[t * 16 + m];
    cb1t[t] = CB1[t * 16 + m];
    cw2t[t] = C2[t * 16 + m];
  }
  const float cb2v = CB2[0];

  char* pl = (char*)(smem + 4608) + w * 4096;  // wave plane: hi@0, lo@+2048
  const char* hB = (const char*)hpk;

  // balanced contiguous tile range: first r waves take q+1 tiles, rest q
  const int gw = blockIdx.x * 12 + w;
  const int nwv = gridDim.x * 12;
  const int q_ = NGRP / nwv;
  const int r_ = NGRP % nwv;
  const int gbeg = gw * q_ + min(gw, r_);
  const int gend = gbeg + q_ + (gw < r_ ? 1 : 0);

  int es = 0, ed = 0;
  if (gbeg < gend) {
    es = ssrc[gbeg * 16 + m];
    ed = sdst[gbeg * 16 + m];
  }

  for (int g = gbeg; g < gend; ++g) {
    const int e0 = g * 16;
    const int ces = es, ced = ed;
    if (g + 1 < gend) {
      es = ssrc[(g + 1) * 16 + m];
      ed = sdst[(g + 1) * 16 + m];
    }

    // ---- gathers: lane's edge-m node rows, frag-ready ----
    i32x4 fh[4], fl[4];
#pragma unroll
    for (int s = 0; s < 4; ++s) {
      const unsigned node = (unsigned)(s < 2 ? ced : ces);
      const unsigned off = node * 256u + (unsigned)((s & 1) * 64 + quad * 16);
      fh[s] = *(const i32x4*)(hB + off);
      fl[s] = *(const i32x4*)(hB + off + 128);
    }

    // ---- per-edge tail data (lanes 0..15) ----
    float rx = 0.f, ry = 0.f, rz = 0.f, d2v = 0.f;
    float ea0 = 0.f, ea1 = 0.f, ea2 = 0.f, ea3 = 0.f;
    if (lane < 16) {
      rx = pos[ced * 3 + 0] - pos[ces * 3 + 0];
      ry = pos[ced * 3 + 1] - pos[ces * 3 + 1];
      rz = pos[ced * 3 + 2] - pos[ces * 3 + 2];
      d2v = rx * rx + ry * ry + rz * rz;
      const float4 ea = seattr[e0 + lane];
      ea0 = ea.x; ea1 = ea.y; ea2 = ea.z; ea3 = ea.w;
    }

    // tail A-frag (k=128..159): quad0 = [d2, ea0..3, 0...], quads 1-3 zero
    i32x4 th, tl;
    {
      float x0 = __shfl(d2v, m), x1 = __shfl(ea0, m), x2 = __shfl(ea1, m),
            x3 = __shfl(ea2, m), x4 = __shfl(ea3, m);
      if (quad) { x0 = x1 = x2 = x3 = x4 = 0.f; }
      float xt[8] = {x0, x1, x2, x3, x4, 0.f, 0.f, 0.f};
      split8(xt, th, tl);
    }

    // ---- GEMV1: m_in[16x160] @ W1[160x64] ----
#pragma unroll
    for (int t = 0; t < 4; ++t) {
      f32x4 P = {eb1t[t], eb1t[t], eb1t[t], eb1t[t]}, Q = {0.f, 0.f, 0.f, 0.f};
#pragma unroll
      for (int s = 0; s < 4; ++s) {
        const i32x4 wh = smem[(s * 4 + t) * 64 + lane];
        const i32x4 wl = smem[1280 + (s * 4 + t) * 64 + lane];
        P = mfma16(fh[s], wh, P);
        Q = mfma16(fh[s], wl, Q);
        Q = mfma16(fl[s], wh, Q);
      }
      {  // tail k-step (s=4)
        const i32x4 wh = smem[(16 + t) * 64 + lane];
        const i32x4 wl = smem[1280 + (16 + t) * 64 + lane];
        P = mfma16(th, wh, P);
        Q = mfma16(th, wl, Q);
        Q = mfma16(tl, wh, Q);
      }
#pragma unroll
      for (int r = 0; r < 4; ++r) {
        const int row = quad * 4 + r;
        const float v = silu_f(P[r] + Q[r]);
        STORE_PAIR(pl, row, t * 32, v);
      }
    }

    // ---- GEMV2: m1[16x64] @ W2[64x64] ----
    i32x4 ah[2], al[2];
#pragma unroll
    for (int s = 0; s < 2; ++s) {
      const int off = m * 128 + ((s * 64 + quad * 16) ^ ((m & 7) << 4));
      ah[s] = *(const i32x4*)(pl + off);
      al[s] = *(const i32x4*)(pl + 2048 + off);
    }
    float mv[4][4];
#pragma unroll
    for (int t = 0; t < 4; ++t) {
      f32x4 P = {eb2t[t], eb2t[t], eb2t[t], eb2t[t]}, Q = {0.f, 0.f, 0.f, 0.f};
#pragma unroll
      for (int s = 0; s < 2; ++s) {
        const i32x4 wh = smem[2560 + (s * 4 + t) * 64 + lane];
        const i32x4 wl = smem[3072 + (s * 4 + t) * 64 + lane];
        P = mfma16(ah[s], wh, P);
        Q = mfma16(ah[s], wl, Q);
        Q = mfma16(al[s], wh, Q);
      }
#pragma unroll
      for (int r = 0; r < 4; ++r) {
        const int row = quad * 4 + r;
        mv[t][r] = silu_f(P[r] + Q[r]);
        STORE_PAIR(pl, row, t * 32, mv[t][r]);  // mm overwrites m1 (in-order DS)
      }
    }

    // ---- segmented agg scatter: runs of equal dst (sorted) reduce in-wave ----
    {
      const bool headp = (m == 0) || (ced != __shfl(ced, lane - 1, 64));
      unsigned rem = (unsigned)(__ballot(headp) & 0xFFFFull);
      while (rem) {
        const int hrow = __ffs((int)rem) - 1;
        rem &= rem - 1;
        const int nrow = rem ? (__ffs((int)rem) - 1) : 16;
        const int dstn = __shfl(ced, hrow, 64);
#pragma unroll
        for (int t = 0; t < 4; ++t) {
          float s = 0.f;
#pragma unroll
          for (int r = 0; r < 4; ++r) {
            const int row = quad * 4 + r;
            s += (row >= hrow && row < nrow) ? mv[t][r] : 0.f;
          }
          s += __shfl_xor(s, 16, 64);
          s += __shfl_xor(s, 32, 64);
          if (quad == 0) atomicAdd(&agg[(size_t)dstn * 64 + t * 16 + m], s);
        }
      }
    }

    // ---- coord MLP: silu(mm @ C1 + cb1) . cw2 summed over 64 cols ----
    i32x4 mh[2], ml[2];
#pragma unroll
    for (int s = 0; s < 2; ++s) {
      const int off = m * 128 + ((s * 64 + quad * 16) ^ ((m & 7) << 4));
      mh[s] = *(const i32x4*)(pl + off);
      ml[s] = *(const i32x4*)(pl + 2048 + off);
    }
    float tr[4] = {0.f, 0.f, 0.f, 0.f};
#pragma unroll
    for (int t = 0; t < 4; ++t) {
      f32x4 P = {cb1t[t], cb1t[t], cb1t[t], cb1t[t]}, Q = {0.f, 0.f, 0.f, 0.f};
#pragma unroll
      for (int s = 0; s < 2; ++s) {
        const i32x4 wh = smem[3584 + (s * 4 + t) * 64 + lane];
        const i32x4 wl = smem[4096 + (s * 4 + t) * 64 + lane];
        P = mfma16(mh[s], wh, P);
        Q = mfma16(mh[s], wl, Q);
        Q = mfma16(ml[s], wh, Q);
      }
#pragma unroll
      for (int r = 0; r < 4; ++r) tr[r] += silu_f(P[r] + Q[r]) * cw2t[t];
    }
#pragma unroll
    for (int mask = 1; mask < 16; mask <<= 1)
#pragma unroll
      for (int r = 0; r < 4; ++r) tr[r] += __shfl_xor(tr[r], mask, 64);

    // posd atomics: lane (rr = m>>2 -> row, cc = m&3 -> coord), per quad
    {
      const int rr = m >> 2, cc = m & 3;
      const int e = quad * 4 + rr;
      const float tv = ((rr & 2) ? ((rr & 1) ? tr[3] : tr[2])
                                 : ((rr & 1) ? tr[1] : tr[0])) + cb2v;
      const int d_ = __shfl(ced, e, 64);
      const float ax = __shfl(rx, e, 64), ay = __shfl(ry, e, 64),
                  az = __shfl(rz, e, 64);
      if (cc < 3) {
        const float rel = cc == 0 ? ax : (cc == 1 ? ay : az);
        atomicAdd(&posd[d_ * 3 + cc], rel * tv);
      }
    }
  }
}

// ---------------- node update kernel (fp32 readlane, 8-node batch) ----------
// MUST stay fp32 (R8: bf16-split here doubled absmax, failed threshold).
// Re-zeroes agg; on the last layer also fuses the batch-pool.
// Grid 512 (R15 best): R16 measured grid 768 (3 blocks/CU) as neutral ->
// k_node is dependent-chain-latency-bound, not TLP-starved; keep best config.
__global__ __launch_bounds__(256) void k_node(
    float* __restrict__ h, unsigned short* __restrict__ hpk,
    float* __restrict__ agg,
    const float* __restrict__ W1, const float* __restrict__ B1,
    const float* __restrict__ W2, const float* __restrict__ B2,
    const int* __restrict__ batch, float* __restrict__ gpool) {
  __shared__ float sW1[128 * 64];
  __shared__ float sW2[64 * 64];
  for (int i = threadIdx.x; i < 128 * 64; i += 256) sW1[i] = W1[i];
  for (int i = threadIdx.x; i < 64 * 64; i += 256) sW2[i] = W2[i];
  __syncthreads();
  const int lane = threadIdx.x & 63;
  const float nb1 = B1[lane], nb2 = B2[lane];
  const int wid = (blockIdx.x * 256 + threadIdx.x) >> 6;
  const int nw = (gridDim.x * 256) >> 6;
  for (int n0 = wid * 8; n0 < NN; n0 += nw * 8) {
    float hj[8], aj[8], a1[8];
#pragma unroll
    for (int i = 0; i < 8; ++i) {
      hj[i] = h[(size_t)(n0 + i) * 64 + lane];
      aj[i] = agg[(size_t)(n0 + i) * 64 + lane];
      a1[i] = nb1;
    }
#pragma unroll
    for (int i = 0; i < 8; ++i) agg[(size_t)(n0 + i) * 64 + lane] = 0.f;
#pragma unroll
    for (int k = 0; k < 64; ++k) {
      const float wv = sW1[k * 64 + lane];
#pragma unroll
      for (int i = 0; i < 8; ++i) a1[i] += rdl(hj[i], k) * wv;
    }
#pragma unroll
    for (int k = 0; k < 64; ++k) {
      const float wv = sW1[(64 + k) * 64 + lane];
#pragma unroll
      for (int i = 0; i < 8; ++i) a1[i] += rdl(aj[i], k) * wv;
    }
    float u[8], a2[8];
#pragma unroll
    for (int i = 0; i < 8; ++i) { u[i] = silu_f(a1[i]); a2[i] = nb2; }
#pragma unroll
    for (int k = 0; k < 64; ++k) {
      const float wv = sW2[k * 64 + lane];
#pragma unroll
      for (int i = 0; i < 8; ++i) a2[i] += rdl(u[i], k) * wv;
    }
    float hn[8];
#pragma unroll
    for (int i = 0; i < 8; ++i) {
      hn[i] = hj[i] + a2[i];
      h[(size_t)(n0 + i) * 64 + lane] = hn[i];
      const unsigned hb = f2u(hn[i]) & 0xffff0000u;
      const float lo = hn[i] - __uint_as_float(hb);
      hpk[(size_t)(n0 + i) * 128 + lane] = (unsigned short)(hb >> 16);
      hpk[(size_t)(n0 + i) * 128 + 64 + lane] = (unsigned short)(f2u(lo) >> 16);
    }
    if (gpool) {  // last layer: fused global-mean-pool accumulation
      float acc = 0.f;
      int curb = batch[n0];
#pragma unroll
      for (int i = 0; i < 8; ++i) {
        const int b = batch[n0 + i];
        if (b != curb) {
          atomicAdd(&gpool[curb * 64 + lane], acc);
          acc = 0.f;
          curb = b;
        }
        acc += hn[i];
      }
      atomicAdd(&gpool[curb * 64 + lane], acc);
    }
  }
}

// ---------------- pooled head: q-circuit + MLP ----------------
__global__ __launch_bounds__(256) void k_final(
    const float* __restrict__ g, const float* __restrict__ gcnt,
    const float* __restrict__ prew, const float* __restrict__ preb,
    const float* __restrict__ qw, const float* __restrict__ pw1,
    const float* __restrict__ pb1, const float* __restrict__ pw2,
    const float* __restrict__ pb2, float* __restrict__ out) {
  const int lane = threadIdx.x & 63;
  const int gid = (blockIdx.x * 256 + threadIdx.x) >> 6;
  if (gid >= NG) return;
  const float cnt = fmaxf(gcnt[gid], 1.f);
  const float gv = g[gid * 64 + lane] / cnt;
  float qin[4];
#pragma unroll
  for (int q = 0; q < 4; ++q)
    qin[q] = wave_sum(gv * prew[lane * 4 + q]) + preb[q];
  float sr[16], si[16];
#pragma unroll
  for (int i = 0; i < 16; ++i) { sr[i] = 0.f; si[i] = 0.f; }
  sr[0] = 1.f;
#pragma unroll
  for (int q = 0; q < 4; ++q) {  // RX(qin[q])
    const int mask = 8 >> q;
    float s, c;
    __sincosf(qin[q] * 0.5f, &s, &c);
#pragma unroll
    for (int i = 0; i < 16; ++i)
      if (!(i & mask)) {
        const int j = i | mask;
        const float ar = sr[i], ai = si[i], br = sr[j], bi = si[j];
        sr[i] = c * ar + s * bi; si[i] = c * ai - s * br;
        sr[j] = c * br + s * ai; si[j] = c * bi - s * ar;
      }
  }
#pragma unroll
  for (int l = 0; l < 2; ++l) {
#pragma unroll
    for (int q = 0; q < 4; ++q) {  // RY(qw[l][q])
      const int mask = 8 >> q;
      float s, c;
      __sincosf(qw[l * 4 + q] * 0.5f, &s, &c);
#pragma unroll
      for (int i = 0; i < 16; ++i)
        if (!(i & mask)) {
          const int j = i | mask;
          const float ar = sr[i], ai = si[i], br = sr[j], bi = si[j];
          sr[i] = c * ar - s * br; si[i] = c * ai - s * bi;
          sr[j] = s * ar + c * br; si[j] = s * ai + c * bi;
        }
    }
#pragma unroll
    for (int q = 0; q < 4; ++q) {  // CNOT q -> (q+1)%4
      const int mc = 8 >> q;
      const int mt = 8 >> ((q + 1) & 3);
#pragma unroll
      for (int i = 0; i < 16; ++i)
        if ((i & mc) && !(i & mt)) {
          const int j = i | mt;
          float t = sr[i]; sr[i] = sr[j]; sr[j] = t;
          t = si[i]; si[i] = si[j]; si[j] = t;
        }
    }
  }
  float qo[4] = {0.f, 0.f, 0.f, 0.f};
#pragma unroll
  for (int i = 0; i < 16; ++i) {
    const float p = sr[i] * sr[i] + si[i] * si[i];
#pragma unroll
    for (int q = 0; q < 4; ++q) qo[q] += ((i >> (3 - q)) & 1) ? -p : p;
  }
  float t = pb1[lane];
#pragma unroll
  for (int q = 0; q < 4; ++q) t += qo[q] * pw1[q * 64 + lane];
  const float r = wave_sum(silu_f(t) * pw2[lane]);
  if (lane == 0) out[gid] = r + pb2[0];
}

extern "C" void kernel_launch(void* const* d_in, const int* in_sizes, int n_in,
                              void* d_out, int out_size, void* d_ws, size_t ws_size,
                              hipStream_t stream) {
  (void)in_sizes; (void)n_in; (void)out_size; (void)ws_size;
  const int*   nt    = (const int*)d_in[0];
  const float* pos0  = (const float*)d_in[1];
  const int*   ei    = (const int*)d_in[2];
  const float* eattr = (const float*)d_in[3];
  const int*   batch = (const int*)d_in[4];
  const float* emb   = (const float*)d_in[5];
  const float* ew1   = (const float*)d_in[6];
  const float* eb1   = (const float*)d_in[7];
  const float* ew2   = (const float*)d_in[8];
  const float* eb2   = (const float*)d_in[9];
  const float* cw1   = (const float*)d_in[10];
  const float* cb1   = (const float*)d_in[11];
  const float* cw2   = (const float*)d_in[12];
  const float* cb2   = (const float*)d_in[13];
  const float* nw1   = (const float*)d_in[14];
  const float* nb1   = (const float*)d_in[15];
  const float* nw2   = (const float*)d_in[16];
  const float* nb2   = (const float*)d_in[17];
  const float* prew  = (const float*)d_in[18];
  const float* preb  = (const float*)d_in[19];
  const float* qw    = (const float*)d_in[20];
  const float* pw1   = (const float*)d_in[21];
  const float* pb1   = (const float*)d_in[22];
  const float* pw2   = (const float*)d_in[23];
  const float* pb2   = (const float*)d_in[24];
  float* out = (float*)d_out;

  float* ws   = (float*)d_ws;
  float* h    = ws;               // NN*64
  float* pos  = h + NN * 64;      // NN*3
  float* posd = pos + NN * 3;     // NN*3
  float* agg  = posd + NN * 3;    // NN*64
  float* deg  = agg + NN * 64;    // NN
  float* g    = deg + NN;         // NG*64
  float* gcnt = g + NG * 64;      // NG
  unsigned short* hpk = (unsigned short*)(gcnt + NG);  // NN*128 bf16 (hi|lo)
  float4* seattr = (float4*)(hpk + NN * 128);          // NE float4 (16B-aligned)
  int* ssrc   = (int*)(seattr + NE);                   // NE
  int* sdst   = ssrc + NE;                             // NE
  int* cursor = sdst + NE;                             // NN
  int* bsum   = cursor + NN;                           // SCANB

  k_prep<<<(NN * 64 + 255) / 256, 256, 0, stream>>>(nt, emb, pos0, pos, deg, g,
                                                    gcnt, agg, posd, h, hpk);
  k_hist<<<(NE + 255) / 256, 256, 0, stream>>>(ei, deg);
  k_scanA<<<SCANB, 1024, 0, stream>>>(deg, cursor, bsum);
  k_scanB<<<SCANB, 1024, 0, stream>>>(cursor, bsum);
  k_scatter<<<(NE + 255) / 256, 256, 0, stream>>>(ei, eattr, cursor, ssrc, sdst,
                                                  seattr);
  k_cnt<<<(NN + 255) / 256, 256, 0, stream>>>(batch, deg, gcnt);
  for (int l = 0; l < NL; ++l) {
    k_edge<<<256, 768, 0, stream>>>(hpk, pos, ssrc, sdst, seattr,
        ew1 + l * 133 * 64, eb1 + l * 64, ew2 + l * 64 * 64, eb2 + l * 64,
        cw1 + l * 64 * 64, cb1 + l * 64, cw2 + l * 64, cb2 + l, agg, posd);
    k_pos<<<(NN * 3 + 255) / 256, 256, 0, stream>>>(pos, posd, deg);
    k_node<<<512, 256, 0, stream>>>(h, hpk, agg, nw1 + l * 128 * 64, nb1 + l * 64,
                                    nw2 + l * 64 * 64, nb2 + l * 64, batch,
                                    (l == NL - 1) ? g : nullptr);
  }
  k_final<<<(NG * 64 + 255) / 256, 256, 0, stream>>>(g, gcnt, prew, preb, qw,
                                                     pw1, pb1, pw2, pb2, out);
}